// Round 17
// baseline (694.056 us; speedup 1.0000x reference)
//
#include <hip/hip_runtime.h>

// MaxUnpooling2D scatter-add, round 17: ABLATION ROUND (R12 structure kept;
// final K2 dispatch is the exact best kernel -> correct output).
// probe<1> x4: zero+gather+LDS-atomics, no store (LDS asm-consumed).
// probe<2> x8: zero+LDS-read+store only (zeros; overwritten by final K2).
// Per-dispatch rocprof rows give the K2 phase split that 4 failed theories
// (R13 occupancy, R14 pipeline, R16 NT) guessed at blind.
//
// dest(in-batch, 22b) = (m & ~255) | c, m = y<<15|x<<8|f (Ho=Wo=128, C=256).
// region r = dest>>13 (512/batch x 8192 floats = 32 KB).
// record = (dest & 8191) << 19 | (f32bits + 0x1000) >> 13   (19-bit float).

typedef float __attribute__((ext_vector_type(4))) f32x4;
typedef int   __attribute__((ext_vector_type(4))) i32x4;
typedef unsigned int u32;
typedef u32 __attribute__((ext_vector_type(4))) u32x4;

constexpr int NIN    = 16 * 64 * 64 * 256;  // 2^24 elements
constexpr int NBIN   = 512;
constexpr int REGION = 8192;                // 32 KB
constexpr int RPB    = 16384;
constexpr int NBLK1  = NIN / RPB;           // 1024
constexpr int TPB1   = 512;
constexpr int SRCB   = (1 << 20) / RPB;     // 64
constexpr int TPB2   = 512;
constexpr int NBLK2  = 16 * NBIN;           // 8192

// ---------------- K1: single-pass block-local counting sort ----------------
__global__ __launch_bounds__(TPB1, 4) void bin_sort(
    const f32x4* __restrict__ upd, const i32x4* __restrict__ msk,
    u32* __restrict__ recs, u32* __restrict__ packed)
{
    __shared__ int hist[NBIN];
    __shared__ int pscan[NBIN];
    __shared__ int cursor[NBIN];
    __shared__ u32 staged[RPB];             // 64 KB

    const int tid = threadIdx.x;
    const int blk = blockIdx.x;
    const int v0  = blk * (RPB / 4);

    hist[tid] = 0;
    __syncthreads();

    u32 pk[32]; int bin[32];
#pragma unroll
    for (int j = 0; j < 8; ++j) {
        const int t = v0 + tid + j * TPB1;
        i32x4 m = __builtin_nontemporal_load(&msk[t]);
        f32x4 u = __builtin_nontemporal_load(&upd[t]);
        const int c = (t << 2) & 255;
        {
            const u32 d = (u32)((m.x & ~255) | c);
            bin[j*4+0] = (int)(d >> 13);
            pk[j*4+0] = ((d & 8191) << 19) | ((__float_as_uint(u.x) + 0x1000) >> 13);
        }
        {
            const u32 d = (u32)((m.y & ~255) | (c + 1));
            bin[j*4+1] = (int)(d >> 13);
            pk[j*4+1] = ((d & 8191) << 19) | ((__float_as_uint(u.y) + 0x1000) >> 13);
        }
        {
            const u32 d = (u32)((m.z & ~255) | (c + 2));
            bin[j*4+2] = (int)(d >> 13);
            pk[j*4+2] = ((d & 8191) << 19) | ((__float_as_uint(u.z) + 0x1000) >> 13);
        }
        {
            const u32 d = (u32)((m.w & ~255) | (c + 3));
            bin[j*4+3] = (int)(d >> 13);
            pk[j*4+3] = ((d & 8191) << 19) | ((__float_as_uint(u.w) + 0x1000) >> 13);
        }
#pragma unroll
        for (int e = 0; e < 4; ++e)
            atomicAdd(&hist[bin[j*4+e]], 1);
    }
    __syncthreads();

    const int h = hist[tid];
    pscan[tid] = h;
    __syncthreads();
    for (int d = 1; d < NBIN; d <<= 1) {
        int v = 0;
        if (tid >= d) v = pscan[tid - d];
        __syncthreads();
        pscan[tid] += v;
        __syncthreads();
    }
    const int excl = pscan[tid] - h;
    cursor[tid] = excl;
    packed[blk * NBIN + tid] = ((u32)excl << 16) | (u32)h;
    __syncthreads();

#pragma unroll
    for (int k = 0; k < 32; ++k)
        staged[atomicAdd(&cursor[bin[k]], 1)] = pk[k];
    __syncthreads();

    u32x4* sg = (u32x4*)staged;
    u32x4* gg = (u32x4*)(recs + (size_t)blk * RPB);
#pragma unroll
    for (int j = 0; j < RPB / 4 / TPB1; ++j)
        gg[tid + j * TPB1] = sg[tid + j * TPB1];
}

// -------- K2 probe: VAR=0 full, VAR=1 gather+atomic only, VAR=2 store only --
template<int VAR, int REP>
__global__ __launch_bounds__(TPB2, 8) void accum_probe(
    const u32* __restrict__ recs, const u32* __restrict__ packed,
    float* __restrict__ out)
{
    __shared__ float region[REGION];        // 32 KB

    const int tid  = threadIdx.x;
    const int lane = tid & 63;
    const int wv   = tid >> 6;
    const int lid = ((blockIdx.x & 7) << 10) | (blockIdx.x >> 3);
    const int b = lid >> 9;
    const int r = lid & (NBIN - 1);

    for (int rep = 0; rep < REP; ++rep) {
        u32 zoff = 0;
        asm volatile("" : "+v"(zoff));      // defeat cross-rep CSE
        const u32* recs_r = recs + zoff;
        const u32* packed_r = packed + zoff;

        f32x4* rv = (f32x4*)region;
#pragma unroll
        for (int j = 0; j < REGION / 4 / TPB2; ++j)
            rv[tid + j * TPB2] = f32x4{0.f, 0.f, 0.f, 0.f};

        u32 pl = 0;
        if (VAR != 2)
            pl = packed_r[(size_t)(b * SRCB + lane) * NBIN + r];
        __syncthreads();

        if (VAR != 2) {
            u32 rec[8]; int cnt[8]; u32 idx[8];
#pragma unroll
            for (int j = 0; j < 8; ++j) {
                const int k = (wv << 3) | j;
                const u32 pj = __shfl(pl, k, 64);
                cnt[j] = (int)(pj & 0xFFFF);
                idx[j] = (u32)((b * SRCB + k) * RPB) + (pj >> 16);
                rec[j] = recs_r[idx[j] + (lane < cnt[j] ? lane : 0)];
            }
#pragma unroll
            for (int j = 0; j < 8; ++j)
                if (lane < cnt[j])
                    atomicAdd(&region[rec[j] >> 19],
                              __uint_as_float((rec[j] & 0x7FFFF) << 13));
#pragma unroll
            for (int j = 0; j < 8; ++j)
                for (int i = 64 + lane; i < cnt[j]; i += 64) {
                    const u32 p = recs_r[idx[j] + i];
                    atomicAdd(&region[p >> 19],
                              __uint_as_float((p & 0x7FFFF) << 13));
                }
        }
        __syncthreads();

        if (VAR == 1) {
            // consume LDS without storing (keep zero+atomics live, rule #17)
#pragma unroll
            for (int j = 0; j < REGION / 4 / TPB2; ++j) {
                f32x4 v = rv[tid + j * TPB2];
                asm volatile("" :: "v"(v.x), "v"(v.y), "v"(v.z), "v"(v.w));
            }
        } else {
            f32x4* og = (f32x4*)(out + ((size_t)b << 22) + ((size_t)r << 13));
#pragma unroll
            for (int j = 0; j < REGION / 4 / TPB2; ++j)
                og[tid + j * TPB2] = rv[tid + j * TPB2];
        }
        if (rep + 1 < REP) __syncthreads();
    }
}

// ---------------- fallback (ws too small): R1 atomic scatter ----------------
__global__ __launch_bounds__(256) void unpool_scatter(
    const f32x4* __restrict__ upd, const i32x4* __restrict__ msk,
    float* __restrict__ out)
{
    const int t = blockIdx.x * 256 + threadIdx.x;
    const int e = t << 2;
    f32x4 u = upd[t];
    i32x4 m = msk[t];
    const int b = e >> 20;
    const int c = e & 255;
    float* ob = out + ((long long)b << 22);
    atomicAdd(ob + ((m.x & ~255) | (c    )), u.x);
    atomicAdd(ob + ((m.y & ~255) | (c + 1)), u.y);
    atomicAdd(ob + ((m.z & ~255) | (c + 2)), u.z);
    atomicAdd(ob + ((m.w & ~255) | (c + 3)), u.w);
}

extern "C" void kernel_launch(void* const* d_in, const int* in_sizes, int n_in,
                              void* d_out, int out_size, void* d_ws, size_t ws_size,
                              hipStream_t stream) {
    const f32x4* upd = (const f32x4*)d_in[0];
    const i32x4* msk = (const i32x4*)d_in[1];
    float* out = (float*)d_out;

    constexpr size_t REC_BYTES = (size_t)NIN * 4;
    constexpr size_t PCK_BYTES = (size_t)NBLK1 * NBIN * sizeof(u32);

    if (ws_size >= REC_BYTES + PCK_BYTES + 4) {
        u32* recs = (u32*)d_ws;
        u32* packed = (u32*)((char*)d_ws + REC_BYTES);
        bin_sort<<<NBLK1, TPB1, 0, stream>>>(upd, msk, recs, packed);
        // ablation probes (idempotent wrt final output):
        accum_probe<1, 4><<<NBLK2, TPB2, 0, stream>>>(recs, packed, out);
        accum_probe<2, 8><<<NBLK2, TPB2, 0, stream>>>(recs, packed, out);
        // final correct pass (exact R12/R16 K2):
        accum_probe<0, 1><<<NBLK2, TPB2, 0, stream>>>(recs, packed, out);
    } else {
        (void)hipMemsetAsync(out, 0, (size_t)out_size * sizeof(float), stream);
        unpool_scatter<<<NIN / 4 / 256, 256, 0, stream>>>(upd, msk, out);
    }
}

// Round 18
// 155.159 us; speedup vs baseline: 4.4732x; 4.4732x over previous
//
#include <hip/hip_runtime.h>

// MaxUnpooling2D scatter-add, round 18: split gather-vs-atomic + fixes.
// R17: K2's 103us = 99.5 (zero+meta+shfl+gather+LDSatomic) + ~3.5 (store,
// hidden). probeC x4 = that phase MINUS atomics -> V_c isolates load side.
// Final K2': transposed meta table (contiguous, scalar loads, no shfl) +
// native ds_add_u32 fixed-point (x2^15) LDS atomics + regular stores.
//
// dest(in-batch, 22b) = (m & ~255) | c, m = y<<15|x<<8|f (Ho=Wo=128, C=256).
// region r = dest>>13 (512/batch x 8192 floats = 32 KB).
// record = (dest & 8191) << 19 | (f32bits + 0x1000) >> 13   (19-bit float).

typedef float __attribute__((ext_vector_type(4))) f32x4;
typedef int   __attribute__((ext_vector_type(4))) i32x4;
typedef unsigned int u32;
typedef u32 __attribute__((ext_vector_type(4))) u32x4;

constexpr int NIN    = 16 * 64 * 64 * 256;  // 2^24 elements
constexpr int NBIN   = 512;
constexpr int REGION = 8192;                // 32 KB
constexpr int RPB    = 16384;
constexpr int NBLK1  = NIN / RPB;           // 1024
constexpr int TPB1   = 512;
constexpr int SRCB   = (1 << 20) / RPB;     // 64
constexpr int TPB2   = 512;
constexpr int NBLK2  = 16 * NBIN;           // 8192

// ---------------- K1: single-pass block-local counting sort ----------------
__global__ __launch_bounds__(TPB1, 4) void bin_sort(
    const f32x4* __restrict__ upd, const i32x4* __restrict__ msk,
    u32* __restrict__ recs, u32* __restrict__ packed, u32* __restrict__ packedT)
{
    __shared__ int hist[NBIN];
    __shared__ int pscan[NBIN];
    __shared__ int cursor[NBIN];
    __shared__ u32 staged[RPB];             // 64 KB

    const int tid = threadIdx.x;
    const int blk = blockIdx.x;
    const int v0  = blk * (RPB / 4);

    hist[tid] = 0;
    __syncthreads();

    u32 pk[32]; int bin[32];
#pragma unroll
    for (int j = 0; j < 8; ++j) {
        const int t = v0 + tid + j * TPB1;
        i32x4 m = __builtin_nontemporal_load(&msk[t]);
        f32x4 u = __builtin_nontemporal_load(&upd[t]);
        const int c = (t << 2) & 255;
        {
            const u32 d = (u32)((m.x & ~255) | c);
            bin[j*4+0] = (int)(d >> 13);
            pk[j*4+0] = ((d & 8191) << 19) | ((__float_as_uint(u.x) + 0x1000) >> 13);
        }
        {
            const u32 d = (u32)((m.y & ~255) | (c + 1));
            bin[j*4+1] = (int)(d >> 13);
            pk[j*4+1] = ((d & 8191) << 19) | ((__float_as_uint(u.y) + 0x1000) >> 13);
        }
        {
            const u32 d = (u32)((m.z & ~255) | (c + 2));
            bin[j*4+2] = (int)(d >> 13);
            pk[j*4+2] = ((d & 8191) << 19) | ((__float_as_uint(u.z) + 0x1000) >> 13);
        }
        {
            const u32 d = (u32)((m.w & ~255) | (c + 3));
            bin[j*4+3] = (int)(d >> 13);
            pk[j*4+3] = ((d & 8191) << 19) | ((__float_as_uint(u.w) + 0x1000) >> 13);
        }
#pragma unroll
        for (int e = 0; e < 4; ++e)
            atomicAdd(&hist[bin[j*4+e]], 1);
    }
    __syncthreads();

    const int h = hist[tid];
    pscan[tid] = h;
    __syncthreads();
    for (int d = 1; d < NBIN; d <<= 1) {
        int v = 0;
        if (tid >= d) v = pscan[tid - d];
        __syncthreads();
        pscan[tid] += v;
        __syncthreads();
    }
    const int excl = pscan[tid] - h;
    cursor[tid] = excl;
    const u32 ent = ((u32)excl << 16) | (u32)h;
    packed[blk * NBIN + tid] = ent;              // block-major (probeC path)
    packedT[(size_t)tid * NBLK1 + blk] = ent;    // bin-major (K2' path)
    __syncthreads();

#pragma unroll
    for (int k = 0; k < 32; ++k)
        staged[atomicAdd(&cursor[bin[k]], 1)] = pk[k];
    __syncthreads();

    u32x4* sg = (u32x4*)staged;
    u32x4* gg = (u32x4*)(recs + (size_t)blk * RPB);
#pragma unroll
    for (int j = 0; j < RPB / 4 / TPB1; ++j)
        gg[tid + j * TPB1] = sg[tid + j * TPB1];
}

// ---- probeC: R15-probe1 structure MINUS atomics (loads asm-consumed) ----
__global__ __launch_bounds__(TPB2, 8) void probeC(
    const u32* __restrict__ recs, const u32* __restrict__ packed)
{
    __shared__ float region[REGION];

    const int tid  = threadIdx.x;
    const int lane = tid & 63;
    const int wv   = tid >> 6;
    const int lid = ((blockIdx.x & 7) << 10) | (blockIdx.x >> 3);
    const int b = lid >> 9;
    const int r = lid & (NBIN - 1);

    for (int rep = 0; rep < 4; ++rep) {
        u32 zoff = 0;
        asm volatile("" : "+v"(zoff));
        const u32* recs_r = recs + zoff;
        const u32* packed_r = packed + zoff;

        f32x4* rv = (f32x4*)region;
#pragma unroll
        for (int j = 0; j < REGION / 4 / TPB2; ++j)
            rv[tid + j * TPB2] = f32x4{0.f, 0.f, 0.f, 0.f};

        const u32 pl = packed_r[(size_t)(b * SRCB + lane) * NBIN + r];
        __syncthreads();

        u32 rec[8]; int cnt[8]; u32 idx[8];
#pragma unroll
        for (int j = 0; j < 8; ++j) {
            const int k = (wv << 3) | j;
            const u32 pj = __shfl(pl, k, 64);
            cnt[j] = (int)(pj & 0xFFFF);
            idx[j] = (u32)((b * SRCB + k) * RPB) + (pj >> 16);
            rec[j] = recs_r[idx[j] + (lane < cnt[j] ? lane : 0)];
        }
#pragma unroll
        for (int j = 0; j < 8; ++j)
            asm volatile("" :: "v"(rec[j]));
#pragma unroll
        for (int j = 0; j < 8; ++j)
            for (int i = 64 + lane; i < cnt[j]; i += 64) {
                u32 p = recs_r[idx[j] + i];
                asm volatile("" :: "v"(p));
            }
        __syncthreads();
        float keep = region[tid];            // keep zero-fill live
        asm volatile("" :: "v"(keep));
        __syncthreads();
    }
}

// ------ K2': contiguous meta (no shfl) + ds_add_u32 fixed-point atomics -----
__global__ __launch_bounds__(TPB2, 8) void accumulate(
    const u32* __restrict__ recs, const u32* __restrict__ packedT,
    float* __restrict__ out)
{
    __shared__ int region[REGION];          // 32 KB (fixed-point x2^15)

    const int tid  = threadIdx.x;
    const int lane = tid & 63;
    const int wv   = tid >> 6;
    const int lid = ((blockIdx.x & 7) << 10) | (blockIdx.x >> 3);
    const int b = lid >> 9;
    const int r = lid & (NBIN - 1);

    i32x4* rv = (i32x4*)region;
#pragma unroll
    for (int j = 0; j < REGION / 4 / TPB2; ++j)
        rv[tid + j * TPB2] = i32x4{0, 0, 0, 0};

    // chunk meta: 64 contiguous u32 per block, wave-uniform scalar reads
    const u32* mt = packedT + (size_t)r * NBLK1 + b * SRCB;
    u32 rec[8]; int cnt[8]; u32 idx[8];
#pragma unroll
    for (int j = 0; j < 8; ++j) {
        const int k = (wv << 3) | j;
        const u32 pj = mt[k];
        cnt[j] = (int)(pj & 0xFFFF);
        idx[j] = (u32)((b * SRCB + k) * RPB) + (pj >> 16);
        rec[j] = recs[idx[j] + (lane < cnt[j] ? lane : 0)];  // safe overread
    }
    __syncthreads();                        // zero visible before atomics

#pragma unroll
    for (int j = 0; j < 8; ++j)
        if (lane < cnt[j]) {
            const float v = __uint_as_float((rec[j] & 0x7FFFF) << 13);
            atomicAdd(&region[rec[j] >> 19], __float2int_rn(v * 32768.f));
        }
#pragma unroll
    for (int j = 0; j < 8; ++j)
        for (int i = 64 + lane; i < cnt[j]; i += 64) {
            const u32 p = recs[idx[j] + i];
            const float v = __uint_as_float((p & 0x7FFFF) << 13);
            atomicAdd(&region[p >> 19], __float2int_rn(v * 32768.f));
        }
    __syncthreads();

    f32x4* og = (f32x4*)(out + ((size_t)b << 22) + ((size_t)r << 13));
#pragma unroll
    for (int j = 0; j < REGION / 4 / TPB2; ++j) {
        const i32x4 iv = rv[tid + j * TPB2];
        og[tid + j * TPB2] = f32x4{iv.x * (1.f / 32768.f), iv.y * (1.f / 32768.f),
                                   iv.z * (1.f / 32768.f), iv.w * (1.f / 32768.f)};
    }
}

// ---------------- fallback (ws too small): R1 atomic scatter ----------------
__global__ __launch_bounds__(256) void unpool_scatter(
    const f32x4* __restrict__ upd, const i32x4* __restrict__ msk,
    float* __restrict__ out)
{
    const int t = blockIdx.x * 256 + threadIdx.x;
    const int e = t << 2;
    f32x4 u = upd[t];
    i32x4 m = msk[t];
    const int b = e >> 20;
    const int c = e & 255;
    float* ob = out + ((long long)b << 22);
    atomicAdd(ob + ((m.x & ~255) | (c    )), u.x);
    atomicAdd(ob + ((m.y & ~255) | (c + 1)), u.y);
    atomicAdd(ob + ((m.z & ~255) | (c + 2)), u.z);
    atomicAdd(ob + ((m.w & ~255) | (c + 3)), u.w);
}

extern "C" void kernel_launch(void* const* d_in, const int* in_sizes, int n_in,
                              void* d_out, int out_size, void* d_ws, size_t ws_size,
                              hipStream_t stream) {
    const f32x4* upd = (const f32x4*)d_in[0];
    const i32x4* msk = (const i32x4*)d_in[1];
    float* out = (float*)d_out;

    constexpr size_t REC_BYTES = (size_t)NIN * 4;                    // 64 MiB
    constexpr size_t PCK_BYTES = (size_t)NBLK1 * NBIN * sizeof(u32); // 2 MiB

    if (ws_size >= REC_BYTES + 2 * PCK_BYTES + 4) {
        u32* recs    = (u32*)d_ws;
        u32* packed  = (u32*)((char*)d_ws + REC_BYTES);
        u32* packedT = (u32*)((char*)d_ws + REC_BYTES + PCK_BYTES);
        bin_sort<<<NBLK1, TPB1, 0, stream>>>(upd, msk, recs, packed, packedT);
        probeC<<<NBLK2, TPB2, 0, stream>>>(recs, packed);   // diagnostic x4
        accumulate<<<NBLK2, TPB2, 0, stream>>>(recs, packedT, out);
    } else {
        (void)hipMemsetAsync(out, 0, (size_t)out_size * sizeof(float), stream);
        unpool_scatter<<<NIN / 4 / 256, 256, 0, stream>>>(upd, msk, out);
    }
}

// Round 19
// 97.542 us; speedup vs baseline: 7.1155x; 1.5907x over previous
//
#include <hip/hip_runtime.h>

// MaxUnpooling2D scatter-add, round 19: CLEAN build of the R18 design
// (probes removed). K1 counting-sort -> recs + bin-major meta table.
// K2': wave-uniform contiguous meta loads (no divergent 64-line load, no
// shfl chain) + native int ds_add fixed-point (x2^15) LDS atomics + regular
// stores. This cleanly times what R18's diagnostic left ambiguous.
//
// dest(in-batch, 22b) = (m & ~255) | c, m = y<<15|x<<8|f (Ho=Wo=128, C=256).
// region r = dest>>13 (512/batch x 8192 floats = 32 KB).
// record = (dest & 8191) << 19 | (f32bits + 0x1000) >> 13   (19-bit float).

typedef float __attribute__((ext_vector_type(4))) f32x4;
typedef int   __attribute__((ext_vector_type(4))) i32x4;
typedef unsigned int u32;
typedef u32 __attribute__((ext_vector_type(4))) u32x4;

constexpr int NIN    = 16 * 64 * 64 * 256;  // 2^24 elements
constexpr int NBIN   = 512;
constexpr int REGION = 8192;                // 32 KB
constexpr int RPB    = 16384;
constexpr int NBLK1  = NIN / RPB;           // 1024
constexpr int TPB1   = 512;
constexpr int SRCB   = (1 << 20) / RPB;     // 64
constexpr int TPB2   = 512;
constexpr int NBLK2  = 16 * NBIN;           // 8192

// ---------------- K1: single-pass block-local counting sort ----------------
__global__ __launch_bounds__(TPB1, 4) void bin_sort(
    const f32x4* __restrict__ upd, const i32x4* __restrict__ msk,
    u32* __restrict__ recs, u32* __restrict__ packedT)
{
    __shared__ int hist[NBIN];
    __shared__ int pscan[NBIN];
    __shared__ int cursor[NBIN];
    __shared__ u32 staged[RPB];             // 64 KB

    const int tid = threadIdx.x;
    const int blk = blockIdx.x;
    const int v0  = blk * (RPB / 4);

    hist[tid] = 0;
    __syncthreads();

    u32 pk[32]; int bin[32];
#pragma unroll
    for (int j = 0; j < 8; ++j) {
        const int t = v0 + tid + j * TPB1;
        i32x4 m = __builtin_nontemporal_load(&msk[t]);
        f32x4 u = __builtin_nontemporal_load(&upd[t]);
        const int c = (t << 2) & 255;
        {
            const u32 d = (u32)((m.x & ~255) | c);
            bin[j*4+0] = (int)(d >> 13);
            pk[j*4+0] = ((d & 8191) << 19) | ((__float_as_uint(u.x) + 0x1000) >> 13);
        }
        {
            const u32 d = (u32)((m.y & ~255) | (c + 1));
            bin[j*4+1] = (int)(d >> 13);
            pk[j*4+1] = ((d & 8191) << 19) | ((__float_as_uint(u.y) + 0x1000) >> 13);
        }
        {
            const u32 d = (u32)((m.z & ~255) | (c + 2));
            bin[j*4+2] = (int)(d >> 13);
            pk[j*4+2] = ((d & 8191) << 19) | ((__float_as_uint(u.z) + 0x1000) >> 13);
        }
        {
            const u32 d = (u32)((m.w & ~255) | (c + 3));
            bin[j*4+3] = (int)(d >> 13);
            pk[j*4+3] = ((d & 8191) << 19) | ((__float_as_uint(u.w) + 0x1000) >> 13);
        }
#pragma unroll
        for (int e = 0; e < 4; ++e)
            atomicAdd(&hist[bin[j*4+e]], 1);
    }
    __syncthreads();

    const int h = hist[tid];
    pscan[tid] = h;
    __syncthreads();
    for (int d = 1; d < NBIN; d <<= 1) {
        int v = 0;
        if (tid >= d) v = pscan[tid - d];
        __syncthreads();
        pscan[tid] += v;
        __syncthreads();
    }
    const int excl = pscan[tid] - h;
    cursor[tid] = excl;
    packedT[(size_t)tid * NBLK1 + blk] = ((u32)excl << 16) | (u32)h; // bin-major
    __syncthreads();

#pragma unroll
    for (int k = 0; k < 32; ++k)
        staged[atomicAdd(&cursor[bin[k]], 1)] = pk[k];
    __syncthreads();

    u32x4* sg = (u32x4*)staged;
    u32x4* gg = (u32x4*)(recs + (size_t)blk * RPB);
#pragma unroll
    for (int j = 0; j < RPB / 4 / TPB1; ++j)
        gg[tid + j * TPB1] = sg[tid + j * TPB1];
}

// ------ K2': contiguous meta (no shfl) + ds_add fixed-point atomics ------
__global__ __launch_bounds__(TPB2, 8) void accumulate(
    const u32* __restrict__ recs, const u32* __restrict__ packedT,
    float* __restrict__ out)
{
    __shared__ int region[REGION];          // 32 KB (fixed-point x2^15)

    const int tid  = threadIdx.x;
    const int lane = tid & 63;
    const int wv   = tid >> 6;
    // XCD-bijective swizzle: consecutive logical regions share an XCD L2.
    const int lid = ((blockIdx.x & 7) << 10) | (blockIdx.x >> 3);
    const int b = lid >> 9;
    const int r = lid & (NBIN - 1);

    i32x4* rv = (i32x4*)region;
#pragma unroll
    for (int j = 0; j < REGION / 4 / TPB2; ++j)
        rv[tid + j * TPB2] = i32x4{0, 0, 0, 0};

    // chunk meta: 64 contiguous u32 per block, wave-uniform scalar reads
    const u32* mt = packedT + (size_t)r * NBLK1 + b * SRCB;
    u32 rec[8]; int cnt[8]; u32 idx[8];
#pragma unroll
    for (int j = 0; j < 8; ++j) {
        const int k = (wv << 3) | j;
        const u32 pj = mt[k];
        cnt[j] = (int)(pj & 0xFFFF);
        idx[j] = (u32)((b * SRCB + k) * RPB) + (pj >> 16);
        rec[j] = recs[idx[j] + (lane < cnt[j] ? lane : 0)];  // safe overread
    }
    __syncthreads();                        // zero visible before atomics

#pragma unroll
    for (int j = 0; j < 8; ++j)
        if (lane < cnt[j]) {
            const float v = __uint_as_float((rec[j] & 0x7FFFF) << 13);
            atomicAdd(&region[rec[j] >> 19], __float2int_rn(v * 32768.f));
        }
#pragma unroll
    for (int j = 0; j < 8; ++j)
        for (int i = 64 + lane; i < cnt[j]; i += 64) {
            const u32 p = recs[idx[j] + i];
            const float v = __uint_as_float((p & 0x7FFFF) << 13);
            atomicAdd(&region[p >> 19], __float2int_rn(v * 32768.f));
        }
    __syncthreads();

    f32x4* og = (f32x4*)(out + ((size_t)b << 22) + ((size_t)r << 13));
#pragma unroll
    for (int j = 0; j < REGION / 4 / TPB2; ++j) {
        const i32x4 iv = rv[tid + j * TPB2];
        og[tid + j * TPB2] = f32x4{iv.x * (1.f / 32768.f), iv.y * (1.f / 32768.f),
                                   iv.z * (1.f / 32768.f), iv.w * (1.f / 32768.f)};
    }
}

// ---------------- fallback (ws too small): R1 atomic scatter ----------------
__global__ __launch_bounds__(256) void unpool_scatter(
    const f32x4* __restrict__ upd, const i32x4* __restrict__ msk,
    float* __restrict__ out)
{
    const int t = blockIdx.x * 256 + threadIdx.x;
    const int e = t << 2;
    f32x4 u = upd[t];
    i32x4 m = msk[t];
    const int b = e >> 20;
    const int c = e & 255;
    float* ob = out + ((long long)b << 22);
    atomicAdd(ob + ((m.x & ~255) | (c    )), u.x);
    atomicAdd(ob + ((m.y & ~255) | (c + 1)), u.y);
    atomicAdd(ob + ((m.z & ~255) | (c + 2)), u.z);
    atomicAdd(ob + ((m.w & ~255) | (c + 3)), u.w);
}

extern "C" void kernel_launch(void* const* d_in, const int* in_sizes, int n_in,
                              void* d_out, int out_size, void* d_ws, size_t ws_size,
                              hipStream_t stream) {
    const f32x4* upd = (const f32x4*)d_in[0];
    const i32x4* msk = (const i32x4*)d_in[1];
    float* out = (float*)d_out;

    constexpr size_t REC_BYTES = (size_t)NIN * 4;                    // 64 MiB
    constexpr size_t PCK_BYTES = (size_t)NBLK1 * NBIN * sizeof(u32); // 2 MiB

    if (ws_size >= REC_BYTES + PCK_BYTES + 4) {
        u32* recs    = (u32*)d_ws;
        u32* packedT = (u32*)((char*)d_ws + REC_BYTES);
        bin_sort<<<NBLK1, TPB1, 0, stream>>>(upd, msk, recs, packedT);
        accumulate<<<NBLK2, TPB2, 0, stream>>>(recs, packedT, out);
    } else {
        (void)hipMemsetAsync(out, 0, (size_t)out_size * sizeof(float), stream);
        unpool_scatter<<<NIN / 4 / 256, 256, 0, stream>>>(upd, msk, out);
    }
}

// Round 20
// 97.116 us; speedup vs baseline: 7.1466x; 1.0044x over previous
//
#include <hip/hip_runtime.h>

// MaxUnpooling2D scatter-add, round 20: R19 (97.5us = K1 39 + K2' 58) with
// K1's 18-barrier Hillis-Steele scan replaced by wave-shuffle scan (2
// barriers). Everything else identical to R19 (best).
//
// Structure floor: 134R(in) + 66W+34R(recs rt) + 2W(meta) + 268W(out)
// ~= 504 MB => ~75-80us at achievable BW. R19 at 97.5 = 1.25x.
//
// dest(in-batch, 22b) = (m & ~255) | c, m = y<<15|x<<8|f (Ho=Wo=128, C=256).
// region r = dest>>13 (512/batch x 8192 floats = 32 KB).
// record = (dest & 8191) << 19 | (f32bits + 0x1000) >> 13   (19-bit float).

typedef float __attribute__((ext_vector_type(4))) f32x4;
typedef int   __attribute__((ext_vector_type(4))) i32x4;
typedef unsigned int u32;
typedef u32 __attribute__((ext_vector_type(4))) u32x4;

constexpr int NIN    = 16 * 64 * 64 * 256;  // 2^24 elements
constexpr int NBIN   = 512;
constexpr int REGION = 8192;                // 32 KB
constexpr int RPB    = 16384;
constexpr int NBLK1  = NIN / RPB;           // 1024
constexpr int TPB1   = 512;
constexpr int SRCB   = (1 << 20) / RPB;     // 64
constexpr int TPB2   = 512;
constexpr int NBLK2  = 16 * NBIN;           // 8192

// ---------------- K1: single-pass block-local counting sort ----------------
__global__ __launch_bounds__(TPB1, 4) void bin_sort(
    const f32x4* __restrict__ upd, const i32x4* __restrict__ msk,
    u32* __restrict__ recs, u32* __restrict__ packedT)
{
    __shared__ int hist[NBIN];
    __shared__ int cursor[NBIN];
    __shared__ int wavesum[8];
    __shared__ u32 staged[RPB];             // 64 KB

    const int tid  = threadIdx.x;
    const int lane = tid & 63;
    const int wv   = tid >> 6;              // 0..7
    const int blk  = blockIdx.x;
    const int v0   = blk * (RPB / 4);

    hist[tid] = 0;                          // NBIN == TPB1
    __syncthreads();

    u32 pk[32]; int bin[32];
#pragma unroll
    for (int j = 0; j < 8; ++j) {
        const int t = v0 + tid + j * TPB1;
        i32x4 m = __builtin_nontemporal_load(&msk[t]);
        f32x4 u = __builtin_nontemporal_load(&upd[t]);
        const int c = (t << 2) & 255;
        {
            const u32 d = (u32)((m.x & ~255) | c);
            bin[j*4+0] = (int)(d >> 13);
            pk[j*4+0] = ((d & 8191) << 19) | ((__float_as_uint(u.x) + 0x1000) >> 13);
        }
        {
            const u32 d = (u32)((m.y & ~255) | (c + 1));
            bin[j*4+1] = (int)(d >> 13);
            pk[j*4+1] = ((d & 8191) << 19) | ((__float_as_uint(u.y) + 0x1000) >> 13);
        }
        {
            const u32 d = (u32)((m.z & ~255) | (c + 2));
            bin[j*4+2] = (int)(d >> 13);
            pk[j*4+2] = ((d & 8191) << 19) | ((__float_as_uint(u.z) + 0x1000) >> 13);
        }
        {
            const u32 d = (u32)((m.w & ~255) | (c + 3));
            bin[j*4+3] = (int)(d >> 13);
            pk[j*4+3] = ((d & 8191) << 19) | ((__float_as_uint(u.w) + 0x1000) >> 13);
        }
#pragma unroll
        for (int e = 0; e < 4; ++e)
            atomicAdd(&hist[bin[j*4+e]], 1);
    }
    __syncthreads();

    // exclusive prefix over 512 bins: wave-shuffle scan, 2 barriers
    const int h = hist[tid];
    int s = h;
#pragma unroll
    for (int d = 1; d < 64; d <<= 1) {
        const int v = __shfl_up(s, d, 64);
        if (lane >= d) s += v;
    }
    if (lane == 63) wavesum[wv] = s;
    __syncthreads();
    int woff = 0;
#pragma unroll
    for (int k = 0; k < 7; ++k)
        if (k < wv) woff += wavesum[k];
    const int excl = woff + s - h;
    cursor[tid] = excl;
    packedT[(size_t)tid * NBLK1 + blk] = ((u32)excl << 16) | (u32)h; // bin-major
    __syncthreads();

#pragma unroll
    for (int k = 0; k < 32; ++k)
        staged[atomicAdd(&cursor[bin[k]], 1)] = pk[k];
    __syncthreads();

    u32x4* sg = (u32x4*)staged;
    u32x4* gg = (u32x4*)(recs + (size_t)blk * RPB);
#pragma unroll
    for (int j = 0; j < RPB / 4 / TPB1; ++j)
        gg[tid + j * TPB1] = sg[tid + j * TPB1];
}

// ------ K2': contiguous meta (no shfl) + ds_add fixed-point atomics ------
__global__ __launch_bounds__(TPB2, 8) void accumulate(
    const u32* __restrict__ recs, const u32* __restrict__ packedT,
    float* __restrict__ out)
{
    __shared__ int region[REGION];          // 32 KB (fixed-point x2^15)

    const int tid  = threadIdx.x;
    const int lane = tid & 63;
    const int wv   = tid >> 6;
    // XCD-bijective swizzle: consecutive logical regions share an XCD L2.
    const int lid = ((blockIdx.x & 7) << 10) | (blockIdx.x >> 3);
    const int b = lid >> 9;
    const int r = lid & (NBIN - 1);

    i32x4* rv = (i32x4*)region;
#pragma unroll
    for (int j = 0; j < REGION / 4 / TPB2; ++j)
        rv[tid + j * TPB2] = i32x4{0, 0, 0, 0};

    // chunk meta: 64 contiguous u32 per block, wave-uniform scalar reads
    const u32* mt = packedT + (size_t)r * NBLK1 + b * SRCB;
    u32 rec[8]; int cnt[8]; u32 idx[8];
#pragma unroll
    for (int j = 0; j < 8; ++j) {
        const int k = (wv << 3) | j;
        const u32 pj = mt[k];
        cnt[j] = (int)(pj & 0xFFFF);
        idx[j] = (u32)((b * SRCB + k) * RPB) + (pj >> 16);
        rec[j] = recs[idx[j] + (lane < cnt[j] ? lane : 0)];  // safe overread
    }
    __syncthreads();                        // zero visible before atomics

#pragma unroll
    for (int j = 0; j < 8; ++j)
        if (lane < cnt[j]) {
            const float v = __uint_as_float((rec[j] & 0x7FFFF) << 13);
            atomicAdd(&region[rec[j] >> 19], __float2int_rn(v * 32768.f));
        }
#pragma unroll
    for (int j = 0; j < 8; ++j)
        for (int i = 64 + lane; i < cnt[j]; i += 64) {
            const u32 p = recs[idx[j] + i];
            const float v = __uint_as_float((p & 0x7FFFF) << 13);
            atomicAdd(&region[p >> 19], __float2int_rn(v * 32768.f));
        }
    __syncthreads();

    f32x4* og = (f32x4*)(out + ((size_t)b << 22) + ((size_t)r << 13));
#pragma unroll
    for (int j = 0; j < REGION / 4 / TPB2; ++j) {
        const i32x4 iv = rv[tid + j * TPB2];
        og[tid + j * TPB2] = f32x4{iv.x * (1.f / 32768.f), iv.y * (1.f / 32768.f),
                                   iv.z * (1.f / 32768.f), iv.w * (1.f / 32768.f)};
    }
}

// ---------------- fallback (ws too small): R1 atomic scatter ----------------
__global__ __launch_bounds__(256) void unpool_scatter(
    const f32x4* __restrict__ upd, const i32x4* __restrict__ msk,
    float* __restrict__ out)
{
    const int t = blockIdx.x * 256 + threadIdx.x;
    const int e = t << 2;
    f32x4 u = upd[t];
    i32x4 m = msk[t];
    const int b = e >> 20;
    const int c = e & 255;
    float* ob = out + ((long long)b << 22);
    atomicAdd(ob + ((m.x & ~255) | (c    )), u.x);
    atomicAdd(ob + ((m.y & ~255) | (c + 1)), u.y);
    atomicAdd(ob + ((m.z & ~255) | (c + 2)), u.z);
    atomicAdd(ob + ((m.w & ~255) | (c + 3)), u.w);
}

extern "C" void kernel_launch(void* const* d_in, const int* in_sizes, int n_in,
                              void* d_out, int out_size, void* d_ws, size_t ws_size,
                              hipStream_t stream) {
    const f32x4* upd = (const f32x4*)d_in[0];
    const i32x4* msk = (const i32x4*)d_in[1];
    float* out = (float*)d_out;

    constexpr size_t REC_BYTES = (size_t)NIN * 4;                    // 64 MiB
    constexpr size_t PCK_BYTES = (size_t)NBLK1 * NBIN * sizeof(u32); // 2 MiB

    if (ws_size >= REC_BYTES + PCK_BYTES + 4) {
        u32* recs    = (u32*)d_ws;
        u32* packedT = (u32*)((char*)d_ws + REC_BYTES);
        bin_sort<<<NBLK1, TPB1, 0, stream>>>(upd, msk, recs, packedT);
        accumulate<<<NBLK2, TPB2, 0, stream>>>(recs, packedT, out);
    } else {
        (void)hipMemsetAsync(out, 0, (size_t)out_size * sizeof(float), stream);
        unpool_scatter<<<NIN / 4 / 256, 256, 0, stream>>>(upd, msk, out);
    }
}